// Round 4
// baseline (855.541 us; speedup 1.0000x reference)
//
#include <hip/hip_runtime.h>
#include <hip/hip_bf16.h>

// Round 6:
//  - GEMMs: 2-phase double-buffered prefetch (T3-min: stage next tile before
//    compute, ONE barrier per K-step) + swapped MFMA operands so epilogue is
//    ushort4/float4 vector stores instead of 64 scalar stores/lane.
//  - flash_pv: swapped QK (lane owns 4 consecutive k-cols of one q-row) ->
//    v_cvt_pk_bf16_f32 packed uint2 P writes (16 scalar ds_write -> 4), mask
//    only the diagonal k-tile; swapped PV -> ctxt rows per-lane (no linv
//    shuffle broadcast), uint2 bf16 stores. Split-K over kt parity kept.
//  - attn_write: swapped operands -> float4 attn stores (4x fewer store instrs).

constexpr int B = 2, L = 2048, D = 1024, H = 16, HD = 64;
constexpr float SCALE = 0.125f;  // 64^-0.5
constexpr int M_ROWS = B * L;    // 4096

typedef short sh8 __attribute__((ext_vector_type(8)));   // 8 x bf16 bits (4 VGPR)
typedef float f32x4 __attribute__((ext_vector_type(4))); // MFMA C/D

__device__ __forceinline__ unsigned short f2bf(float f) {
  union { float f; unsigned u; } x; x.f = f;
  unsigned r = x.u + 0x7FFFu + ((x.u >> 16) & 1u);  // RNE
  return (unsigned short)(r >> 16);
}
__device__ __forceinline__ float bf2f(unsigned short u) {
  union { unsigned u; float f; } x; x.u = ((unsigned)u) << 16;
  return x.f;
}
// packed RNE f32x2 -> bf16x2 (lo = a, hi = b)
__device__ __forceinline__ unsigned pack_bf16(float a, float b) {
  unsigned r;
  asm("v_cvt_pk_bf16_f32 %0, %1, %2" : "=v"(r) : "v"(a), "v"(b));
  return r;
}

// async global->LDS, 16B per lane; lds dest = wave-uniform base + lane*16
#define GLL16(gsrc, ldsbase)                                                  \
  __builtin_amdgcn_global_load_lds(                                           \
      (const __attribute__((address_space(1))) void*)(gsrc),                  \
      (__attribute__((address_space(3))) void*)(ldsbase), 16, 0, 0)

// ---------------- casts ----------------
__global__ __launch_bounds__(256) void cast_x_bf16(const float* __restrict__ in,
                                                   unsigned short* __restrict__ out) {
  const size_t g = (size_t)blockIdx.x * 256 + threadIdx.x;  // 8 floats each
  const float4 a = *(const float4*)&in[g * 8];
  const float4 b = *(const float4*)&in[g * 8 + 4];
  ushort4 o0, o1;
  o0.x = f2bf(a.x); o0.y = f2bf(a.y); o0.z = f2bf(a.z); o0.w = f2bf(a.w);
  o1.x = f2bf(b.x); o1.y = f2bf(b.y); o1.z = f2bf(b.z); o1.w = f2bf(b.w);
  *(ushort4*)&out[g * 8] = o0;
  *(ushort4*)&out[g * 8 + 4] = o1;
}

__global__ __launch_bounds__(256) void cast_w4_bf16(
    const float* __restrict__ wq, const float* __restrict__ wk,
    const float* __restrict__ wv, const float* __restrict__ wo,
    unsigned short* __restrict__ out) {
  const int z = blockIdx.z;
  const float* src = (z == 0) ? wq : (z == 1) ? wk : (z == 2) ? wv : wo;
  unsigned short* dst = out + (size_t)z * 1024 * 1024;
  const size_t g = (size_t)blockIdx.x * 256 + threadIdx.x;
  const float4 a = *(const float4*)&src[g * 8];
  const float4 b = *(const float4*)&src[g * 8 + 4];
  ushort4 o0, o1;
  o0.x = f2bf(a.x); o0.y = f2bf(a.y); o0.z = f2bf(a.z); o0.w = f2bf(a.w);
  o1.x = f2bf(b.x); o1.y = f2bf(b.y); o1.z = f2bf(b.z); o1.w = f2bf(b.w);
  *(ushort4*)&dst[g * 8] = o0;
  *(ushort4*)&dst[g * 8 + 4] = o1;
}

// ------------- LDS-staged bf16 MFMA GEMM: Y[m,n] = alpha * sum_k A[m,k]*W[n,k] -------------
// 128x128 block tile, BK=64, 4 waves (2x2 of 64x64). Double-buffered prefetch:
// stage(t+1) issued BEFORE compute(t); one barrier (vmcnt0+lgkmcnt0) per K-step.
// Swapped MFMA operands: acc[i][j] = mfma(Wfrag[j], Xfrag[i]) -> lane holds
// Y[R+i*16+m][C+j*16+kg*4+reg] -> vector epilogue stores.
template <bool BF16OUT>
__device__ __forceinline__ void gemm_lds_body(
    const unsigned short* __restrict__ A, const unsigned short* __restrict__ W,
    void* __restrict__ Y, float alpha) {
  __shared__ __align__(16) unsigned short As[2][128 * 64];
  __shared__ __align__(16) unsigned short Ws[2][128 * 64];
  const int tid = threadIdx.x;
  const int wave = tid >> 6, lane = tid & 63;
  const int m = lane & 15, kg = lane >> 4;
  const int m0 = blockIdx.y * 128, n0 = blockIdx.x * 128;
  const int wr = wave >> 1, wc = wave & 1;
  const int srow = lane >> 3;   // 0..7: row within 8-row staging group
  const int schunk = lane & 7;  // 16B chunk (8 elems) within 64-elem row

  f32x4 acc[4][4];
#pragma unroll
  for (int i = 0; i < 4; ++i)
#pragma unroll
    for (int j = 0; j < 4; ++j) acc[i][j] = (f32x4){0.f, 0.f, 0.f, 0.f};

  // pre-swizzled source chunk: LDS chunk c holds global chunk c^(row&7)
  const int sch = (schunk ^ srow) * 8;

  auto stage = [&](int buf, int k0) {
#pragma unroll
    for (int c = 0; c < 4; ++c) {
      const int grp = wave * 4 + c;
      const int row = grp * 8 + srow;
      GLL16(A + (size_t)(m0 + row) * 1024 + k0 + sch, (char*)&As[buf][0] + grp * 1024);
      GLL16(W + (size_t)(n0 + row) * 1024 + k0 + sch, (char*)&Ws[buf][0] + grp * 1024);
    }
  };

  stage(0, 0);
  __syncthreads();

  for (int t = 0; t < 16; ++t) {
    const int cur = t & 1;
    if (t < 15) stage(cur ^ 1, (t + 1) * 64);  // prefetch next K-tile
    sh8 af[4][2], bfr[4][2];
#pragma unroll
    for (int i = 0; i < 4; ++i) {
      const int ra = wr * 64 + i * 16 + m;
      const int rb = wc * 64 + i * 16 + m;
      const int x7 = m & 7;  // == row&7 for both
#pragma unroll
      for (int s = 0; s < 2; ++s) {
        const int ch = ((s * 4 + kg) ^ x7) * 8;  // de-swizzled chunk
        af[i][s]  = *(const sh8*)&As[cur][ra * 64 + ch];
        bfr[i][s] = *(const sh8*)&Ws[cur][rb * 64 + ch];
      }
    }
#pragma unroll
    for (int s = 0; s < 2; ++s)
#pragma unroll
      for (int i = 0; i < 4; ++i)
#pragma unroll
        for (int j = 0; j < 4; ++j)
          acc[i][j] = __builtin_amdgcn_mfma_f32_16x16x32_bf16(bfr[j][s], af[i][s],
                                                             acc[i][j], 0, 0, 0);
    __syncthreads();  // vmcnt(0): prefetch landed; lgkmcnt(0): reads of cur done
  }

  const int R = m0 + wr * 64, C0 = n0 + wc * 64;
#pragma unroll
  for (int i = 0; i < 4; ++i) {
    const int row = R + i * 16 + m;
#pragma unroll
    for (int j = 0; j < 4; ++j) {
      const int col = C0 + j * 16 + kg * 4;
      if constexpr (BF16OUT) {
        uint2 o;
        o.x = pack_bf16(acc[i][j][0] * alpha, acc[i][j][1] * alpha);
        o.y = pack_bf16(acc[i][j][2] * alpha, acc[i][j][3] * alpha);
        *(uint2*)&((unsigned short*)Y)[(size_t)row * 1024 + col] = o;
      } else {
        float4 o;
        o.x = acc[i][j][0] * alpha; o.y = acc[i][j][1] * alpha;
        o.z = acc[i][j][2] * alpha; o.w = acc[i][j][3] * alpha;
        *(float4*)&((float*)Y)[(size_t)row * 1024 + col] = o;
      }
    }
  }
}

__global__ __launch_bounds__(256) void proj_mfma(
    const unsigned short* __restrict__ xb, const unsigned short* __restrict__ wb4,
    unsigned short* __restrict__ qpre, unsigned short* __restrict__ kpre,
    unsigned short* __restrict__ vpre) {
  const int z = blockIdx.z;
  const unsigned short* W = wb4 + (size_t)z * 1024 * 1024;
  unsigned short* Yo = (z == 0) ? qpre : (z == 1) ? kpre : vpre;
  gemm_lds_body<true>(xb, W, Yo, (z == 1) ? SCALE : 1.0f);
}

__global__ __launch_bounds__(256) void outproj_mfma(
    const unsigned short* __restrict__ ctxtb, const unsigned short* __restrict__ wob,
    float* __restrict__ out) {
  gemm_lds_body<false>(ctxtb, wob, out, 1.0f);
}

// ---------------- depthwise conv-3 (bf16 in) -> bf16 row-major (for Q, K) ----------------
__global__ __launch_bounds__(256) void dwconv_bf16(const unsigned short* __restrict__ in,
                                                   const float* __restrict__ w,
                                                   const float* __restrict__ bias,
                                                   unsigned short* __restrict__ out) {
  const int gid = blockIdx.x * 256 + threadIdx.x;  // over B*L*(D/4)
  const int d4 = gid % (D / 4);
  const int l = (gid / (D / 4)) % L;
  const int b = gid / ((D / 4) * L);
  const int d = d4 * 4;
  const size_t base = ((size_t)b * L + l) * D + d;
  const ushort4 cu = *(const ushort4*)&in[base];
  ushort4 pu = make_ushort4(0, 0, 0, 0), nu = make_ushort4(0, 0, 0, 0);
  if (l > 0) pu = *(const ushort4*)&in[base - D];
  if (l < L - 1) nu = *(const ushort4*)&in[base + D];
  float o0 = w[(d + 0) * 3 + 0] * bf2f(pu.x) + w[(d + 0) * 3 + 1] * bf2f(cu.x) + w[(d + 0) * 3 + 2] * bf2f(nu.x) + bias[d + 0];
  float o1 = w[(d + 1) * 3 + 0] * bf2f(pu.y) + w[(d + 1) * 3 + 1] * bf2f(cu.y) + w[(d + 1) * 3 + 2] * bf2f(nu.y) + bias[d + 1];
  float o2 = w[(d + 2) * 3 + 0] * bf2f(pu.z) + w[(d + 2) * 3 + 1] * bf2f(cu.z) + w[(d + 2) * 3 + 2] * bf2f(nu.z) + bias[d + 2];
  float o3 = w[(d + 3) * 3 + 0] * bf2f(pu.w) + w[(d + 3) * 3 + 1] * bf2f(cu.w) + w[(d + 3) * 3 + 2] * bf2f(nu.w) + bias[d + 3];
  ushort4 o;
  o.x = f2bf(o0); o.y = f2bf(o1); o.z = f2bf(o2); o.w = f2bf(o3);
  *(ushort4*)&out[base] = o;
}

// ------- depthwise conv-3 for V (bf16 in) -> bf16 transposed [b][h][hd][L] -------
__global__ __launch_bounds__(256) void dwconv_v_t(const unsigned short* __restrict__ in,
                                                  const float* __restrict__ w,
                                                  const float* __restrict__ bias,
                                                  unsigned short* __restrict__ vt) {
  const int l0 = blockIdx.x * 64;
  const int h = blockIdx.y, b = blockIdx.z;
  const int d0 = h * HD;
  __shared__ unsigned short T[64][72];  // [d][l], padded
  const int tid = threadIdx.x;
  const int dq = (tid & 15) * 4, lr = tid >> 4;
#pragma unroll
  for (int pass = 0; pass < 4; ++pass) {
    const int l = l0 + pass * 16 + lr;
    const size_t base = ((size_t)b * L + l) * D + d0 + dq;
    const ushort4 cu = *(const ushort4*)&in[base];
    ushort4 pu = make_ushort4(0, 0, 0, 0), nu = make_ushort4(0, 0, 0, 0);
    if (l > 0) pu = *(const ushort4*)&in[base - D];
    if (l < L - 1) nu = *(const ushort4*)&in[base + D];
    const float c[4] = {bf2f(cu.x), bf2f(cu.y), bf2f(cu.z), bf2f(cu.w)};
    const float pp[4] = {bf2f(pu.x), bf2f(pu.y), bf2f(pu.z), bf2f(pu.w)};
    const float nn[4] = {bf2f(nu.x), bf2f(nu.y), bf2f(nu.z), bf2f(nu.w)};
#pragma unroll
    for (int j = 0; j < 4; ++j) {
      const int d = d0 + dq + j;
      float o = w[d * 3 + 0] * pp[j] + w[d * 3 + 1] * c[j] + w[d * 3 + 2] * nn[j] + bias[d];
      T[dq + j][pass * 16 + lr] = f2bf(o);
    }
  }
  __syncthreads();
  const int dd = tid >> 2, lq = (tid & 3) * 16;
  const size_t rbase = ((size_t)(b * H + h) * HD + dd) * L + l0 + lq;
#pragma unroll
  for (int i = 0; i < 16; i += 4) {
    ushort4 o;
    o.x = T[dd][lq + i + 0]; o.y = T[dd][lq + i + 1];
    o.z = T[dd][lq + i + 2]; o.w = T[dd][lq + i + 3];
    *(ushort4*)&vt[rbase + i] = o;
  }
}

// ---------------- single-pass flash, split-K over kt parity, swapped operands ----------------
// grid: (16 pairs, H, B); block 512 = 8 waves. wg=wave&3 owns 16 q-rows (q-row = r0+m);
// half=wave>>2 does kt = half, half+2, ... Diagonal k-tile handled separately (only
// place masking is needed). QK: mfma(K,Q) -> lane holds P[q-row m][4 consecutive k-cols].
// PV: mfma(V,P) -> lane holds ctxt[q-row m][4 consecutive d]. No linv broadcast needed.
__global__ __launch_bounds__(512) void flash_pv(
    const unsigned short* __restrict__ qb, const unsigned short* __restrict__ kb,
    const unsigned short* __restrict__ vt, float* __restrict__ linv_g,
    unsigned short* __restrict__ ctxtb) {
  const int p = blockIdx.x, h = blockIdx.y, b = blockIdx.z;
  const int tid = threadIdx.x;
  const int wave = tid >> 6, lane = tid & 63;
  const int wg = wave & 3, half = wave >> 2;
  const int m = lane & 15, kg = lane >> 4;

  __shared__ unsigned short P_sh[8][16 * 72];  // per-wave P tile [qrow][kcol]
  __shared__ float cpart[64 * 68];             // half-1 cacc staging [qrow][d]
  __shared__ float lpart[64];                  // half-1 row sums

  const size_t bh = (size_t)b * H + h;
  const unsigned short* qbase = qb + (size_t)b * L * D + h * HD;
  const unsigned short* kbase = kb + (size_t)b * L * D + h * HD;
  const unsigned short* vbase = vt + bh * HD * L;
  float* lbase = linv_g + bh * L;

  for (int which = 0; which < 2; ++which) {
    const int qt = which ? (31 - p) : p;
    const int q0 = qt * 64;
    const int r0 = q0 + wg * 16;
    const int row_q = r0 + m;

    sh8 qf[2];
#pragma unroll
    for (int s = 0; s < 2; ++s)
      qf[s] = *(const sh8*)(qbase + (size_t)row_q * D + s * 32 + kg * 8);

    f32x4 cacc[4];
#pragma unroll
    for (int ct = 0; ct < 4; ++ct) cacc[ct] = (f32x4){0.f, 0.f, 0.f, 0.f};
    float lsum = 0.f;

    auto do_tile = [&](int kcol0, bool mask) {
#pragma unroll
      for (int ct = 0; ct < 4; ++ct) {
        f32x4 sacc = {0.f, 0.f, 0.f, 0.f};
#pragma unroll
        for (int s = 0; s < 2; ++s) {
          sh8 kf = *(const sh8*)(kbase + (size_t)(kcol0 + ct * 16 + m) * D + s * 32 + kg * 8);
          sacc = __builtin_amdgcn_mfma_f32_16x16x32_bf16(kf, qf[s], sacc, 0, 0, 0);
        }
        float e[4];
#pragma unroll
        for (int reg = 0; reg < 4; ++reg) {
          float v = __expf(sacc[reg]);
          if (mask) {
            const int col = kcol0 + ct * 16 + kg * 4 + reg;
            v = (col <= row_q) ? v : 0.f;
          }
          e[reg] = v;
          lsum += v;
        }
        uint2 pk;
        pk.x = pack_bf16(e[0], e[1]);
        pk.y = pack_bf16(e[2], e[3]);
        *(uint2*)&P_sh[wave][m * 72 + ct * 16 + kg * 4] = pk;
      }
      sh8 pf[2];
#pragma unroll
      for (int s = 0; s < 2; ++s)
        pf[s] = *(const sh8*)&P_sh[wave][m * 72 + s * 32 + kg * 8];
#pragma unroll
      for (int ct = 0; ct < 4; ++ct) {
#pragma unroll
        for (int s = 0; s < 2; ++s) {
          sh8 vf = *(const sh8*)(vbase + (size_t)(ct * 16 + m) * L + kcol0 + s * 32 + kg * 8);
          cacc[ct] = __builtin_amdgcn_mfma_f32_16x16x32_bf16(vf, pf[s], cacc[ct], 0, 0, 0);
        }
      }
    };

    for (int kt = half; kt < qt; kt += 2) do_tile(kt * 64, false);
    if ((qt & 1) == half) do_tile(q0, true);

    // full row-m sum for this half: reduce across kg groups
    lsum += __shfl_xor(lsum, 16);
    lsum += __shfl_xor(lsum, 32);

    if (half == 1) {
      if (kg == 0) lpart[wg * 16 + m] = lsum;
#pragma unroll
      for (int ct = 0; ct < 4; ++ct)
        *(f32x4*)&cpart[(wg * 16 + m) * 68 + ct * 16 + kg * 4] = cacc[ct];
    }
    __syncthreads();
    if (half == 0) {
      const float inv = 1.0f / (lsum + lpart[wg * 16 + m]);
#pragma unroll
      for (int ct = 0; ct < 4; ++ct) {
        const f32x4 cp = *(const f32x4*)&cpart[(wg * 16 + m) * 68 + ct * 16 + kg * 4];
        uint2 o;
        o.x = pack_bf16((cacc[ct][0] + cp[0]) * inv, (cacc[ct][1] + cp[1]) * inv);
        o.y = pack_bf16((cacc[ct][2] + cp[2]) * inv, (cacc[ct][3] + cp[3]) * inv);
        *(uint2*)&ctxtb[(size_t)(b * L + row_q) * D + h * HD + ct * 16 + kg * 4] = o;
      }
      if (kg == 0) lbase[row_q] = inv;
    }
    __syncthreads();
  }
}

// ---------------- attn materializer: attn[row,col] = exp(S)*linv[row] ----------------
// grid (tc=16, tr=16, bh=32); 128x128 tile; 4 waves 2x2 of 64x64. Swapped operands:
// lane holds rows row0+i*16+m, cols col0+j*16+kg*4+{0..3} -> float4 stores.
__global__ __launch_bounds__(256) void attn_write(
    const unsigned short* __restrict__ qb, const unsigned short* __restrict__ kb,
    const float* __restrict__ linv_g, float* __restrict__ attn) {
  const int tc = blockIdx.x, tr = blockIdx.y, bhz = blockIdx.z;
  const int b = bhz >> 4, h = bhz & 15;
  float* attnb = attn + (size_t)bhz * L * L;

  if (tc > tr) {  // strictly-upper tile: zeros
    const int t = threadIdx.x;
    const int r = tr * 128 + (t >> 1);
    float* rp = attnb + (size_t)r * L + tc * 128 + (t & 1) * 64;
    const float4 z4 = make_float4(0, 0, 0, 0);
#pragma unroll
    for (int i = 0; i < 16; ++i) *(float4*)&rp[i * 4] = z4;
    return;
  }

  const int tid = threadIdx.x;
  const int wave = tid >> 6, lane = tid & 63;
  const int m = lane & 15, kg = lane >> 4;
  const int wr = wave >> 1, wc = wave & 1;
  const unsigned short* qbase = qb + (size_t)b * L * D + h * HD;
  const unsigned short* kbase = kb + (size_t)b * L * D + h * HD;
  const float* lbase = linv_g + (size_t)bhz * L;
  const int row0 = tr * 128 + wr * 64, col0 = tc * 128 + wc * 64;

  sh8 qf[4][2];
#pragma unroll
  for (int i = 0; i < 4; ++i)
#pragma unroll
    for (int s = 0; s < 2; ++s)
      qf[i][s] = *(const sh8*)(qbase + (size_t)(row0 + i * 16 + m) * D + s * 32 + kg * 8);

  f32x4 acc[4][4];
#pragma unroll
  for (int i = 0; i < 4; ++i)
#pragma unroll
    for (int j = 0; j < 4; ++j) acc[i][j] = (f32x4){0.f, 0.f, 0.f, 0.f};

#pragma unroll
  for (int s = 0; s < 2; ++s)
#pragma unroll
    for (int j = 0; j < 4; ++j) {
      sh8 kf = *(const sh8*)(kbase + (size_t)(col0 + j * 16 + m) * D + s * 32 + kg * 8);
#pragma unroll
      for (int i = 0; i < 4; ++i)
        acc[i][j] = __builtin_amdgcn_mfma_f32_16x16x32_bf16(kf, qf[i][s], acc[i][j], 0, 0, 0);
    }

  const bool diag = (tc == tr);
#pragma unroll
  for (int i = 0; i < 4; ++i) {
    const int row = row0 + i * 16 + m;
    const float li = lbase[row];
    float* rowp = attnb + (size_t)row * L;
#pragma unroll
    for (int j = 0; j < 4; ++j) {
      const int cbase = col0 + j * 16 + kg * 4;
      float4 o;
      float v0 = __expf(acc[i][j][0]) * li;
      float v1 = __expf(acc[i][j][1]) * li;
      float v2 = __expf(acc[i][j][2]) * li;
      float v3 = __expf(acc[i][j][3]) * li;
      if (diag) {
        v0 = (cbase + 0 <= row) ? v0 : 0.f;
        v1 = (cbase + 1 <= row) ? v1 : 0.f;
        v2 = (cbase + 2 <= row) ? v2 : 0.f;
        v3 = (cbase + 3 <= row) ? v3 : 0.f;
      }
      o.x = v0; o.y = v1; o.z = v2; o.w = v3;
      *(float4*)&rowp[cbase] = o;
    }
  }
}

extern "C" void kernel_launch(void* const* d_in, const int* in_sizes, int n_in,
                              void* d_out, int out_size, void* d_ws, size_t ws_size,
                              hipStream_t stream) {
  const float* x    = (const float*)d_in[0];
  const float* wq   = (const float*)d_in[1];
  const float* wk   = (const float*)d_in[2];
  const float* wv   = (const float*)d_in[3];
  const float* wo   = (const float*)d_in[4];
  const float* cq_w = (const float*)d_in[5];
  const float* cq_b = (const float*)d_in[6];
  const float* ck_w = (const float*)d_in[7];
  const float* ck_b = (const float*)d_in[8];
  const float* cv_w = (const float*)d_in[9];
  const float* cv_b = (const float*)d_in[10];

  float* out  = (float*)d_out;                       // [B,L,D]
  float* attn = (float*)d_out + (size_t)B * L * D;   // [B,H,L,L]

  const size_t bufN = (size_t)B * L * D;  // 4,194,304 elems
  unsigned short* ws16 = (unsigned short*)d_ws;
  unsigned short* qpre  = ws16 + 0 * bufN;
  unsigned short* kpre  = ws16 + 1 * bufN;
  unsigned short* vpre  = ws16 + 2 * bufN;
  unsigned short* qb    = ws16 + 3 * bufN;
  unsigned short* kbb   = ws16 + 4 * bufN;
  unsigned short* vtb   = ws16 + 5 * bufN;
  unsigned short* ctxtb = ws16 + 6 * bufN;
  unsigned short* xb    = ws16 + 7 * bufN;
  unsigned short* wb4   = ws16 + 8 * bufN;            // 4 x 1024x1024 bf16
  float* linv_g = (float*)(ws16 + 9 * bufN);          // [B*H][L] = 256 KiB
  // total ws use: 75.75 MiB

  // 0) casts to bf16
  cast_x_bf16<<<2048, 256, 0, stream>>>(x, xb);
  cast_w4_bf16<<<dim3(512, 1, 4), 256, 0, stream>>>(wq, wk, wv, wo, wb4);
  // 1) QKV projections via LDS-staged MFMA (k pre-scaled by SCALE), bf16 out
  proj_mfma<<<dim3(1024 / 128, M_ROWS / 128, 3), 256, 0, stream>>>(
      xb, wb4, qpre, kpre, vpre);
  // 2) depthwise conv-3 -> bf16
  const int convBlocks = (B * L * (D / 4)) / 256;  // 4096
  dwconv_bf16<<<convBlocks, 256, 0, stream>>>(qpre, cq_w, cq_b, qb);
  dwconv_bf16<<<convBlocks, 256, 0, stream>>>(kpre, ck_w, ck_b, kbb);
  dwconv_v_t<<<dim3(L / 64, H, B), 256, 0, stream>>>(vpre, cv_w, cv_b, vtb);
  // 3) single-pass flash (split-K): ctxt bf16 + linv
  flash_pv<<<dim3(16, H, B), 512, 0, stream>>>(qb, kbb, vtb, linv_g, ctxtb);
  // 4) attn materializer (write-bound)
  attn_write<<<dim3(16, 16, B * H), 256, 0, stream>>>(qb, kbb, linv_g, attn);
  // 5) output projection via LDS-staged MFMA
  outproj_mfma<<<dim3(1024 / 128, M_ROWS / 128, 1), 256, 0, stream>>>(
      ctxtb, wb4 + 3ull * 1024 * 1024, out);
}